// Round 8
// baseline (125.997 us; speedup 1.0000x reference)
//
#include <hip/hip_runtime.h>

// LCN spiking net, round 13: r12 structure + register-prefetched weights.
//  - r12 (125.4us best): async l0 stage + 2 blocks/CU. Node count (4) and
//    grids settled by r10/r11.
//  - This round: hide kn/w/b load latency under the stage barriers.
//    l0: preload both outputs' 25 idx+w into VGPRs BEFORE the async stage;
//        post-barrier gather is LDS+FMA only.
//    tail: prefetch l3/l4/FC weights before the h3 stage; drop the s5 LDS
//        round-trip + one barrier (FC consumes l4 result in-register);
//        block 512 = 8 waves -> 256-VGPR budget fits the prefetch (~160).
//  - l1/l2 byte-identical to r12.

#define ROWS 32
#define TSTEPS 20
#define D0 14400
#define D1 7200
#define D2 3600
#define D3 1800
#define D4 900
#define D5 450
#define KNB 25

typedef __attribute__((address_space(1))) const void gas_void;
typedef __attribute__((address_space(3))) void las_void;

// one output's 25 indices + weights + bias, held in registers
struct KW25 {
    int4   k[6];
    float4 w[6];
    int    kt;
    float  wt;
    float  b;
};

__device__ __forceinline__ void load_kw25(KW25& a, const int* __restrict__ kp,
                                          const float* __restrict__ wp, float bv)
{
#pragma unroll
    for (int q = 0; q < 6; ++q) {
        __builtin_memcpy(&a.k[q], kp + 4 * q, 16);
        __builtin_memcpy(&a.w[q], wp + 4 * q, 16);
    }
    a.kt = kp[24]; a.wt = wp[24]; a.b = bv;
}

__device__ __forceinline__ float dot25_lds(const KW25& a, const float* s)
{
    float acc = a.b;
#pragma unroll
    for (int q = 0; q < 6; ++q) {
        acc += s[a.k[q].x] * a.w[q].x + s[a.k[q].y] * a.w[q].y
             + s[a.k[q].z] * a.w[q].z + s[a.k[q].w] * a.w[q].w;
    }
    return acc + s[a.kt] * a.wt;
}

// 25-element transposed-layout gather: pin[(idx<<5)+r], 16B kn/w loads.
#define GATHER25_T(acc, kp, wp, pin, r)                             \
    {                                                               \
        _Pragma("unroll")                                           \
        for (int k = 0; k < 24; k += 4) {                           \
            int4   ki; __builtin_memcpy(&ki, (kp) + k, 16);         \
            float4 wi; __builtin_memcpy(&wi, (wp) + k, 16);         \
            acc += (pin)[(ki.x << 5) + (r)] * wi.x                  \
                 + (pin)[(ki.y << 5) + (r)] * wi.y                  \
                 + (pin)[(ki.z << 5) + (r)] * wi.z                  \
                 + (pin)[(ki.w << 5) + (r)] * wi.w;                 \
        }                                                           \
        acc += (pin)[((kp)[24] << 5) + (r)] * (wp)[24];             \
    }

// K1: layer 0. Grid (16, ROWS) = 512 blocks, 256 threads, 2 blocks/CU.
// Prefetch kn/w/b into regs, async global->LDS stage of the 57.6KB x row,
// then LDS+FMA-only gather, write h1t transposed.
__global__ __launch_bounds__(256)
void l0_stage(const float* __restrict__ x, float* __restrict__ h1t,
              const float* __restrict__ w, const float* __restrict__ bvec,
              const int* __restrict__ knn)
{
    __shared__ float s[D0];   // 57.6 KB
    const int r = blockIdx.y;
    const int tid = threadIdx.x;
    const float* xrow = x + ((size_t)r * TSTEPS + (TSTEPS - 1)) * (size_t)D0;

    const int j0 = blockIdx.x * 450;
    const int jA = j0 + tid;                                   // tid < 256 < 450: always valid
    const int tB = (tid + 256 < 450) ? tid + 256 : 449;        // clamp keeps loads in-bounds
    const int jB = j0 + tB;

    KW25 A, B;
    load_kw25(A, knn + jA * KNB, w + jA * KNB, bvec[jA]);
    load_kw25(B, knn + jB * KNB, w + jB * KNB, bvec[jB]);

    // async stage: 16B per lane per iter, LDS dst = wave-uniform base + lane*16
    {
        const float4* src = reinterpret_cast<const float4*>(xrow);
        float4* dst = reinterpret_cast<float4*>(s);
#pragma unroll 1
        for (int i = tid; i < D0 / 4; i += 256) {
            __builtin_amdgcn_global_load_lds((gas_void*)(src + i),
                                             (las_void*)(dst + (i & ~63)),
                                             16, 0, 0);
        }
    }
    __syncthreads();   // vmcnt(0) drain: stage AND prefetch both complete here

    h1t[(jA << 5) + r] = dot25_lds(A, s);
    if (tid < 450 - 256)
        h1t[(jB << 5) + r] = dot25_lds(B, s);
}

// K2: transposed gather -> transposed write.
// pout[j][r] = b[j] + sum_k pin[knn[j][k]][r]*w[j][k]
// Wave = 2 outputs x 32 rows; gather = 1 contiguous 128B line per half-wave.
__global__ __launch_bounds__(256)
void layer_t_k(const float* __restrict__ pin, float* __restrict__ pout,
               const float* __restrict__ w, const float* __restrict__ bvec,
               const int* __restrict__ knn, int npairs)
{
    const int lane = threadIdx.x & 63;
    const int r  = lane & 31;
    const int jj = lane >> 5;
    const int nw = gridDim.x << 2;
#pragma unroll 1
    for (int jp = (blockIdx.x << 2) + (threadIdx.x >> 6); jp < npairs; jp += nw) {
        const int j = (jp << 1) + jj;
        const int*   kn = knn + j * KNB;
        const float* ww = w   + j * KNB;
        float acc = bvec[j];
        GATHER25_T(acc, kn, ww, pin, r)
        pout[(j << 5) + r] = acc;
    }
}

// K3: transposed gather -> ROW-major write (for the tail's coalesced stage).
__global__ __launch_bounds__(256)
void layer_t_k_rm(const float* __restrict__ pin, float* __restrict__ pout,
                  const float* __restrict__ w, const float* __restrict__ bvec,
                  const int* __restrict__ knn, int npairs, int dout)
{
    const int lane = threadIdx.x & 63;
    const int r  = lane & 31;
    const int jj = lane >> 5;
    const int nw = gridDim.x << 2;
#pragma unroll 1
    for (int jp = (blockIdx.x << 2) + (threadIdx.x >> 6); jp < npairs; jp += nw) {
        const int j = (jp << 1) + jj;
        const int*   kn = knn + j * KNB;
        const float* ww = w   + j * KNB;
        float acc = bvec[j];
        GATHER25_T(acc, kn, ww, pin, r)
        pout[r * dout + j] = acc;   // row-major scatter (spread full-chip)
    }
}

// K4: layers 3-4 + FC, one block per row (32 x 512, 8 waves -> 256-VGPR budget).
// Prefetch all weights before the stage barrier; l3 split over 2 register
// sets; FC consumes the l4 result in-register (no s5, one less barrier).
__global__ __launch_bounds__(512)
void tail34fc(const float* __restrict__ h3,
              const float* __restrict__ w3, const float* __restrict__ b3, const int* __restrict__ n3,
              const float* __restrict__ w4, const float* __restrict__ b4, const int* __restrict__ n4,
              const float* __restrict__ Wfc, const float* __restrict__ bfc,
              float* __restrict__ out)
{
    __shared__ float s3[D3];  // 7.2 KB
    __shared__ float s4[D4];  // 3.6 KB
    __shared__ float red[2];

    const int r   = blockIdx.x;
    const int tid = threadIdx.x;

    // prefetch: l3 outputs tid and tid+512 (if <900), l4 output tid (<450), FC pair
    const int t3a = tid;                                        // < 512 < 900: valid
    const int t3b = (tid + 512 < D4) ? tid + 512 : D4 - 1;      // clamp
    const int t4  = (tid < D5) ? tid : D5 - 1;                  // clamp

    KW25 A3a, A3b, A4;
    load_kw25(A3a, n3 + t3a * KNB, w3 + t3a * KNB, b3[t3a]);
    load_kw25(A3b, n3 + t3b * KNB, w3 + t3b * KNB, b3[t3b]);
    load_kw25(A4,  n4 + t4  * KNB, w4 + t4  * KNB, b4[t4]);
    const float wf0 = Wfc[2 * t4 + 0];
    const float wf1 = Wfc[2 * t4 + 1];

    // stage this row of h3 (coalesced float4, 450 lanes, one iteration)
    if (tid < D3 / 4) {
        reinterpret_cast<float4*>(s3)[tid] =
            reinterpret_cast<const float4*>(h3 + (size_t)r * D3)[tid];
    }
    if (tid == 0) { red[0] = bfc[0]; red[1] = bfc[1]; }
    __syncthreads();

    // layer 3: 1800 -> 900 (register weights, LDS+FMA only)
    s4[t3a] = dot25_lds(A3a, s3);
    if (tid + 512 < D4)
        s4[t3b] = dot25_lds(A3b, s3);
    __syncthreads();

    // layer 4 + FC: 900 -> 450 -> 2, result stays in-register
    float c0 = 0.0f, c1 = 0.0f;
    if (tid < D5) {
        const float v = dot25_lds(A4, s4);
        c0 = v * wf0;
        c1 = v * wf1;
    }
#pragma unroll
    for (int off = 32; off > 0; off >>= 1) {
        c0 += __shfl_down(c0, off);
        c1 += __shfl_down(c1, off);
    }
    if ((tid & 63) == 0 && tid < D5) {
        atomicAdd(&red[0], c0);
        atomicAdd(&red[1], c1);
    }
    __syncthreads();
    if (tid < 2)
        out[2 * r + tid] = red[tid];
}

extern "C" void kernel_launch(void* const* d_in, const int* in_sizes, int n_in,
                              void* d_out, int out_size, void* d_ws, size_t ws_size,
                              hipStream_t stream)
{
    const float* x    = (const float*)d_in[0];
    const float* w0   = (const float*)d_in[1];
    const float* b0   = (const float*)d_in[2];
    const int*   knn0 = (const int*)  d_in[3];
    const float* w1   = (const float*)d_in[4];
    const float* b1   = (const float*)d_in[5];
    const int*   knn1 = (const int*)  d_in[6];
    const float* w2   = (const float*)d_in[7];
    const float* b2   = (const float*)d_in[8];
    const int*   knn2 = (const int*)  d_in[9];
    const float* w3   = (const float*)d_in[10];
    const float* b3   = (const float*)d_in[11];
    const int*   knn3 = (const int*)  d_in[12];
    const float* w4   = (const float*)d_in[13];
    const float* b4   = (const float*)d_in[14];
    const int*   knn4 = (const int*)  d_in[15];
    const float* Wfc  = (const float*)d_in[16];
    const float* bfc  = (const float*)d_in[17];
    float* out = (float*)d_out;

    // ws: h1t[D1][32] transposed | h2t[D2][32] transposed | h3[32][D3] row-major
    float* h1t = (float*)d_ws;
    float* h2t = h1t + (size_t)D1 * ROWS;
    float* h3  = h2t + (size_t)D2 * ROWS;

    // layer 0: x[:,T-1,:] -> h1t (transposed), 512 blocks, 2 blocks/CU
    l0_stage<<<dim3(D0 / 900, ROWS), dim3(256), 0, stream>>>(x, h1t, w0, b0, knn0);

    // layer 1: h1t -> h2t (full chip, 1800 pairs, transposed write)
    layer_t_k<<<dim3(450), dim3(256), 0, stream>>>(h1t, h2t, w1, b1, knn1, D2 / 2);

    // layer 2: h2t -> h3 (full chip, 900 pairs, ROW-major write)
    layer_t_k_rm<<<dim3(225), dim3(256), 0, stream>>>(h2t, h3, w2, b2, knn2, D3 / 2, D3);

    // layers 3-4 + FC: one block per row, direct write (no memset)
    tail34fc<<<dim3(ROWS), dim3(512), 0, stream>>>(
        h3,
        w3, b3, knn3,
        w4, b4, knn4,
        Wfc, bfc, out);
}